// Round 2
// baseline (2638.643 us; speedup 1.0000x reference)
//
#include <hip/hip_runtime.h>
#include <math.h>

#define NH 8
#define D 64
#define BB 2
#define SS 2048

// ---------------- Stage 1: per-head projection + optional RoPE ----------------
// grid.x = B*NH*SS, block = 64. dst[b][h][s][d] = sum_z x[b][s][z] * W[h][z][d]
__global__ __launch_bounds__(64) void proj_rope_kernel(
    const float* __restrict__ x, const float* __restrict__ W,
    float* __restrict__ dst, int do_rope) {
    int idx = blockIdx.x;
    int s = idx % SS;
    int h = (idx / SS) % NH;
    int b = idx / (SS * NH);
    int d = threadIdx.x;

    __shared__ float xrow[D];
    xrow[d] = x[((size_t)b * SS + s) * D + d];
    __syncthreads();

    const float* Wp = W + (size_t)h * D * D + d;
    float acc = 0.f;
#pragma unroll
    for (int z = 0; z < D; ++z) acc += xrow[z] * Wp[(size_t)z * D];

    float outv = acc;
    if (do_rope) {
        int i = d >> 1;  // pair index
        float inv_freq = powf(10000.0f, -(float)(2 * i) / 64.0f);
        float angle = (float)s * inv_freq;
        float c = cosf(angle), sn = sinf(angle);
        float partner = __shfl_xor(acc, 1);
        if ((d & 1) == 0) outv = acc * c - partner * sn;   // even: x1*c - x2*s
        else              outv = partner * sn + acc * c;   // odd : x1*s + x2*c
    }
    dst[(((size_t)b * NH + h) * SS + s) * D + d] = outv;
}

// ---------------- Stage 2: per-row softmax stats (max, sum) over k<=q ----------
// grid.x = B*NH*SS (one wave per q-row), block = 64
__global__ __launch_bounds__(64) void rowstats_kernel(
    const float* __restrict__ qh, const float* __restrict__ kh,
    float* __restrict__ rowmax, float* __restrict__ rowsum) {
    int idx = blockIdx.x;            // (b*NH + h)*SS + q
    int q = idx % SS;
    int bh = idx / SS;
    int t = threadIdx.x;

    __shared__ float qrow[D];
    qrow[t] = qh[(size_t)idx * D + t];
    __syncthreads();

    const float* khp = kh + (size_t)bh * SS * D;
    float m = -3.0e38f, ssum = 0.f;
    for (int k = t; k <= q; k += 64) {
        const float* kr = khp + (size_t)k * D;
        float dot = 0.f;
#pragma unroll
        for (int dd = 0; dd < D; ++dd) dot += qrow[dd] * kr[dd];
        dot *= (1.0f / 64.0f);
        if (dot > m) { ssum = ssum * expf(m - dot) + 1.0f; m = dot; }
        else         { ssum += expf(dot - m); }
    }
    // wave combine of (m, ssum)
#pragma unroll
    for (int off = 1; off < 64; off <<= 1) {
        float m2 = __shfl_xor(m, off);
        float s2 = __shfl_xor(ssum, off);
        float M = fmaxf(m, m2);
        ssum = ssum * expf(m - M) + s2 * expf(m2 - M);
        m = M;
    }
    if (t == 0) { rowmax[idx] = m; rowsum[idx] = ssum; }
}

// ---------------- Stage 3: out[k,d] = sum_{q>k} P[q,k] * vh[q,d] ---------------
// grid.x = B*NH*SS (one wave per output position k), block = 64
__global__ __launch_bounds__(64) void av_kernel(
    const float* __restrict__ qh, const float* __restrict__ kh,
    const float* __restrict__ vh,
    const float* __restrict__ rowmax, const float* __restrict__ rowsum,
    float* __restrict__ att) {
    int idx = blockIdx.x;            // (b*NH + h)*SS + k
    int k = idx % SS;
    int bh = idx / SS;
    int h = bh % NH;
    int b = bh / NH;
    int t = threadIdx.x;

    __shared__ float krow[D];
    __shared__ float w[64];
    krow[t] = kh[(size_t)idx * D + t];
    __syncthreads();

    const float* qp = qh + (size_t)bh * SS * D;
    const float* vp = vh + (size_t)bh * SS * D;
    const float* rm = rowmax + (size_t)bh * SS;
    const float* rs = rowsum + (size_t)bh * SS;

    float acc = 0.f;
    for (int q0 = k + 1; q0 < SS; q0 += 64) {
        int q = q0 + t;
        float wv = 0.f;
        if (q < SS) {
            const float* qr = qp + (size_t)q * D;
            float dot = 0.f;
#pragma unroll
            for (int dd = 0; dd < D; ++dd) dot += qr[dd] * krow[dd];
            dot *= (1.0f / 64.0f);
            wv = expf(dot - rm[q]) / rs[q];
        }
        w[t] = wv;
        __syncthreads();
        int lim = min(64, SS - q0);
        for (int j = 0; j < lim; ++j)
            acc += w[j] * vp[(size_t)(q0 + j) * D + t];
        __syncthreads();
    }
    // att laid out as [b][k][h*64 + d] so stage 4 is a plain GEMM
    att[((size_t)b * SS + k) * (NH * D) + (size_t)h * D + t] = acc;
}

// ---------------- Stage 4: final projection: out = att(4096x512) @ W_o(512x64) -
// grid.x = B*SS, block = 64
__global__ __launch_bounds__(64) void outproj_kernel(
    const float* __restrict__ att, const float* __restrict__ Wo,
    float* __restrict__ out) {
    int idx = blockIdx.x;            // b*SS + s
    int t = threadIdx.x;
    __shared__ float row[NH * D];
    const float* ap = att + (size_t)idx * (NH * D);
    for (int z = t; z < NH * D; z += 64) row[z] = ap[z];
    __syncthreads();
    float acc = 0.f;
#pragma unroll 8
    for (int z = 0; z < NH * D; ++z) acc += row[z] * Wo[(size_t)z * D + t];
    out[(size_t)idx * D + t] = acc;
}

extern "C" void kernel_launch(void* const* d_in, const int* in_sizes, int n_in,
                              void* d_out, int out_size, void* d_ws, size_t ws_size,
                              hipStream_t stream) {
    const float* q  = (const float*)d_in[0];
    const float* k  = (const float*)d_in[1];
    const float* v  = (const float*)d_in[2];
    const float* Wq = (const float*)d_in[3];
    const float* Wk = (const float*)d_in[4];
    const float* Wv = (const float*)d_in[5];
    const float* Wo = (const float*)d_in[6];
    float* out = (float*)d_out;

    const size_t PROJ = (size_t)BB * NH * SS * D;   // 2,097,152 floats
    const size_t BHS  = (size_t)BB * NH * SS;       // 32,768

    float* ws   = (float*)d_ws;
    float* qh   = ws;
    float* kh   = qh + PROJ;
    float* vh   = kh + PROJ;
    float* rmax = vh + PROJ;
    float* rsum = rmax + BHS;
    float* att  = rsum + BHS;                       // PROJ floats

    dim3 blk(64);
    dim3 grid_proj(BB * NH * SS);

    proj_rope_kernel<<<grid_proj, blk, 0, stream>>>(q, Wq, qh, 1);
    proj_rope_kernel<<<grid_proj, blk, 0, stream>>>(k, Wk, kh, 1);
    proj_rope_kernel<<<grid_proj, blk, 0, stream>>>(v, Wv, vh, 0);

    rowstats_kernel<<<dim3(BB * NH * SS), blk, 0, stream>>>(qh, kh, rmax, rsum);

    av_kernel<<<dim3(BB * NH * SS), blk, 0, stream>>>(qh, kh, vh, rmax, rsum, att);

    outproj_kernel<<<dim3(BB * SS), blk, 0, stream>>>(att, Wo, out);
}

// Round 3
// 155.251 us; speedup vs baseline: 16.9960x; 16.9960x over previous
//
#include <hip/hip_runtime.h>
#include <math.h>

#define NH 8
#define D 64
#define BB 2
#define SS 2048
#define NBH (BB*NH)
#define LOG2E 1.4426950408889634f

typedef short bf16x8 __attribute__((ext_vector_type(8)));
typedef float f32x4 __attribute__((ext_vector_type(4)));

#define MFMA16(a, b, c) __builtin_amdgcn_mfma_f32_16x16x32_bf16((a), (b), (c), 0, 0, 0)

// round-to-nearest-even f32 -> bf16 (finite inputs)
__device__ inline short f2bf(float f) {
    unsigned u = __float_as_uint(f);
    unsigned r = (u + 0x7fffu + ((u >> 16) & 1u)) >> 16;
    return (short)r;
}

// ---------- Kernel 0: W[h][z][d] fp32 -> WT[h][d][z] bf16 (tiny) -------------
__global__ __launch_bounds__(256) void wtrans_kernel(
    const float* __restrict__ Wq, const float* __restrict__ Wk,
    const float* __restrict__ Wv,
    short* __restrict__ WqT, short* __restrict__ WkT, short* __restrict__ WvT) {
    int blk = blockIdx.x;
    int tensor = blk >> 3, h = blk & 7;
    const float* W = tensor == 0 ? Wq : (tensor == 1 ? Wk : Wv);
    short* WT = tensor == 0 ? WqT : (tensor == 1 ? WkT : WvT);
    __shared__ float wl[64][65];
    int t = threadIdx.x;
    {
        int z = t >> 2, c0 = (t & 3) * 16;
        const float* src = W + (size_t)h * 4096 + (size_t)z * 64 + c0;
#pragma unroll
        for (int i = 0; i < 16; ++i) wl[z][c0 + i] = src[i];
    }
    __syncthreads();
    {
        int d = t >> 2, z0 = (t & 3) * 16;
        short* dst = WT + ((size_t)h * 64 + d) * 64 + z0;
#pragma unroll
        for (int i = 0; i < 16; ++i) dst[i] = f2bf(wl[z0 + i][d]);
    }
}

// ---------- Kernel 1: projection via MFMA (+RoPE for Q/K, +transpose for V) --
// grid = NBH*32 (bh, s-tile), block = 256 (4 waves, wave w -> s rows w*16..+16)
__global__ __launch_bounds__(256) void proj_mfma_kernel(
    const float* __restrict__ x, const short* __restrict__ WT,
    short* __restrict__ dst,   // [bh][s][d] bf16 (mode 1: rope)
    short* __restrict__ dstT,  // [bh][d][s] bf16 (mode 2: transpose, no rope)
    int mode) {
    int blk = blockIdx.x;
    int st = blk & 31, bh = blk >> 5;
    int h = bh & 7, b = bh >> 3;
    int t = threadIdx.x, w = t >> 6, lane = t & 63;
    int l15 = lane & 15, lg = lane >> 4;

    __shared__ short vt[64 * 64];

    // A-frags: x rows (fp32 -> bf16)
    int sA = st * 64 + w * 16 + l15;
    const float* xr = x + ((size_t)b * SS + sA) * D + lg * 8;
    bf16x8 a0, a1;
#pragma unroll
    for (int j = 0; j < 8; ++j) a0[j] = f2bf(xr[j]);
#pragma unroll
    for (int j = 0; j < 8; ++j) a1[j] = f2bf(xr[32 + j]);

    // B-frags from WT (bf16, contiguous)
    bf16x8 bfr[4][2];
#pragma unroll
    for (int ds_ = 0; ds_ < 4; ++ds_) {
        int d = ds_ * 16 + l15;
        const short* wp = WT + ((size_t)h * 64 + d) * 64 + lg * 8;
        bfr[ds_][0] = *(const bf16x8*)(wp);
        bfr[ds_][1] = *(const bf16x8*)(wp + 32);
    }

    f32x4 c[4];
#pragma unroll
    for (int ds_ = 0; ds_ < 4; ++ds_) {
        f32x4 z = {0.f, 0.f, 0.f, 0.f};
        z = MFMA16(a0, bfr[ds_][0], z);
        z = MFMA16(a1, bfr[ds_][1], z);
        c[ds_] = z;
    }

    int sbase = st * 64 + w * 16 + lg * 4;  // + reg = C row (s)
    if (mode == 1) {
        // RoPE + store [bh][s][d]
#pragma unroll
        for (int ds_ = 0; ds_ < 4; ++ds_) {
            int d = ds_ * 16 + l15;
            float invf = exp2f(-(float)(d & ~1) * (13.287712379549449f / 64.0f));
#pragma unroll
            for (int r = 0; r < 4; ++r) {
                float v = c[ds_][r];
                float pr = __shfl_xor(v, 1);
                float ang = (float)(sbase + r) * invf;
                float cs = cosf(ang), sn = sinf(ang);
                float o = (d & 1) ? (pr * sn + v * cs) : (v * cs - pr * sn);
                dst[((size_t)bh * SS + sbase + r) * D + d] = f2bf(o);
            }
        }
    } else {
        // transpose through swizzled LDS, store [bh][d][s]
#pragma unroll
        for (int ds_ = 0; ds_ < 4; ++ds_) {
            int d = ds_ * 16 + l15;
#pragma unroll
            for (int r = 0; r < 4; ++r) {
                int sc = w * 16 + lg * 4 + r;
                vt[d * 64 + (sc ^ ((d & 7) << 3))] = f2bf(c[ds_][r]);
            }
        }
        __syncthreads();
#pragma unroll
        for (int pp = 0; pp < 2; ++pp) {
            int idx = pp * 256 + t;
            int d = idx >> 3, a = idx & 7;
            bf16x8 val = *(const bf16x8*)&vt[d * 64 + ((a ^ (d & 7)) << 3)];
            *(bf16x8*)&dstT[((size_t)bh * D + d) * SS + st * 64 + a * 8] = val;
        }
    }
}

// ---------- Kernel 2: pass 1 — per-q softmax stats via S'[k,q]=mfma(K,Q) -----
// grid = NBH*16 (bh, pair p -> q-tiles {p, 31-p}), block = 256
__global__ __launch_bounds__(256) void colstats_kernel(
    const short* __restrict__ qh, const short* __restrict__ kh,
    float* __restrict__ marr, float* __restrict__ ilarr) {
    int blk = blockIdx.x;
    int p = blk & 15, bh = blk >> 4;
    int t = threadIdx.x, w = t >> 6, lane = t & 63;
    int l15 = lane & 15, lg = lane >> 4;
    __shared__ short kl[64 * 64];

    for (int it = 0; it < 2; ++it) {
        int qt = it ? (31 - p) : p;
        int qcol = qt * 64 + w * 16 + l15;
        const short* qp = qh + ((size_t)bh * SS + qcol) * D + lg * 8;
        bf16x8 qb0 = *(const bf16x8*)qp;
        bf16x8 qb1 = *(const bf16x8*)(qp + 32);

        float m = -3.0e38f, lsum = 0.f;
        for (int kt = 0; kt <= qt; ++kt) {
            __syncthreads();
#pragma unroll
            for (int pp = 0; pp < 2; ++pp) {
                int idx = pp * 256 + t;
                int kr = idx >> 3, a = idx & 7;
                bf16x8 vv = *(const bf16x8*)&kh[((size_t)bh * SS + kt * 64 + kr) * D + a * 8];
                *(bf16x8*)&kl[kr * 64 + ((a ^ (kr & 7)) << 3)] = vv;
            }
            __syncthreads();
            bool diag = (kt == qt);
#pragma unroll
            for (int ks = 0; ks < 4; ++ks) {
                int krow = ks * 16 + l15;
                bf16x8 ka0 = *(const bf16x8*)&kl[krow * 64 + ((lg ^ (krow & 7)) << 3)];
                bf16x8 ka1 = *(const bf16x8*)&kl[krow * 64 + (((4 + lg) ^ (krow & 7)) << 3)];
                f32x4 acc = {0.f, 0.f, 0.f, 0.f};
                acc = MFMA16(ka0, qb0, acc);
                acc = MFMA16(ka1, qb1, acc);
#pragma unroll
                for (int r = 0; r < 4; ++r) {
                    int k = kt * 64 + ks * 16 + lg * 4 + r;
                    if (!diag || k <= qcol) {
                        float v = acc[r] * (1.f / 64.f);
                        float mn = fmaxf(m, v);
                        lsum = lsum * exp2f((m - mn) * LOG2E) + exp2f((v - mn) * LOG2E);
                        m = mn;
                    }
                }
            }
        }
        // combine across the 4 lane-groups (same q col)
#pragma unroll
        for (int off = 16; off <= 32; off <<= 1) {
            float m2 = __shfl_xor(m, off);
            float l2 = __shfl_xor(lsum, off);
            float mn = fmaxf(m, m2);
            lsum = lsum * exp2f((m - mn) * LOG2E) + l2 * exp2f((m2 - mn) * LOG2E);
            m = mn;
        }
        if (lane < 16) {
            marr[(size_t)bh * SS + qcol] = m;
            ilarr[(size_t)bh * SS + qcol] = 1.0f / lsum;
        }
    }
}

// ---------- Kernel 3: pass 2 — out[k,d] = sum_{q>k} P'[k,q] * V[q,d] ---------
// grid = NBH*16 (bh, pair p -> k-tiles {p, 31-p}), block = 256
__global__ __launch_bounds__(256) void pv_kernel(
    const short* __restrict__ qh, const short* __restrict__ kh,
    const short* __restrict__ vhT,
    const float* __restrict__ marr, const float* __restrict__ ilarr,
    float* __restrict__ att) {
    int blk = blockIdx.x;
    int p = blk & 15, bh = blk >> 4;
    int h = bh & 7, b = bh >> 3;
    int t = threadIdx.x, w = t >> 6, lane = t & 63;
    int l15 = lane & 15, lg = lane >> 4;

    __shared__ short ql[64 * 64];
    __shared__ short vl[64 * 64];
    __shared__ short pl[4][16 * 64];
    __shared__ float ml[64], il[64];

    for (int it = 0; it < 2; ++it) {
        int kt = it ? (31 - p) : p;
        int krow = kt * 64 + w * 16 + l15;
        const short* kp = kh + ((size_t)bh * SS + krow) * D + lg * 8;
        bf16x8 ka0 = *(const bf16x8*)kp;
        bf16x8 ka1 = *(const bf16x8*)(kp + 32);

        f32x4 acc[4];
#pragma unroll
        for (int i = 0; i < 4; ++i) acc[i] = (f32x4){0.f, 0.f, 0.f, 0.f};

        for (int qt = kt; qt < 32; ++qt) {
            // stage Q tile and V^T tile (swizzled), plus per-q stats
#pragma unroll
            for (int pp = 0; pp < 2; ++pp) {
                int idx = pp * 256 + t;
                int r = idx >> 3, a = idx & 7;
                *(bf16x8*)&ql[r * 64 + ((a ^ (r & 7)) << 3)] =
                    *(const bf16x8*)&qh[((size_t)bh * SS + qt * 64 + r) * D + a * 8];
                *(bf16x8*)&vl[r * 64 + ((a ^ (r & 7)) << 3)] =
                    *(const bf16x8*)&vhT[((size_t)bh * D + r) * SS + qt * 64 + a * 8];
            }
            if (t < 64) ml[t] = marr[(size_t)bh * SS + qt * 64 + t];
            else if (t < 128) il[t - 64] = ilarr[(size_t)bh * SS + qt * 64 + (t - 64)];
            __syncthreads();

            bool diag = (qt == kt);
            int myk = kt * 64 + w * 16 + lg * 4;  // + r
#pragma unroll
            for (int qs = 0; qs < 4; ++qs) {
                int qrow = qs * 16 + l15;
                bf16x8 qb0 = *(const bf16x8*)&ql[qrow * 64 + ((lg ^ (qrow & 7)) << 3)];
                bf16x8 qb1 = *(const bf16x8*)&ql[qrow * 64 + (((4 + lg) ^ (qrow & 7)) << 3)];
                f32x4 s = {0.f, 0.f, 0.f, 0.f};
                s = MFMA16(ka0, qb0, s);
                s = MFMA16(ka1, qb1, s);
                float mq2 = ml[qrow] * LOG2E;
                float iq = il[qrow];
                int qq = qt * 64 + qrow;
#pragma unroll
                for (int r = 0; r < 4; ++r) {
                    float pv = exp2f(s[r] * (LOG2E / 64.f) - mq2) * iq;
                    if (diag && qq <= myk + r) pv = 0.f;
                    int prow = lg * 4 + r;
                    pl[w][prow * 64 + (qrow ^ ((prow & 7) << 3))] = f2bf(pv);
                }
            }
            // PV: A = P' (wave-private LDS, same-wave DS ops are in-order)
#pragma unroll
            for (int qhh = 0; qhh < 2; ++qhh) {
                int prow = l15;
                bf16x8 pa = *(const bf16x8*)&pl[w][prow * 64 + ((((qhh << 2) | lg) ^ (prow & 7)) << 3)];
#pragma unroll
                for (int ds_ = 0; ds_ < 4; ++ds_) {
                    int dr = ds_ * 16 + l15;
                    bf16x8 vb = *(const bf16x8*)&vl[dr * 64 + ((((qhh << 2) | lg) ^ (dr & 7)) << 3)];
                    acc[ds_] = MFMA16(pa, vb, acc[ds_]);
                }
            }
            __syncthreads();
        }
        // write att[b][k][h*64+d] fp32
#pragma unroll
        for (int ds_ = 0; ds_ < 4; ++ds_) {
            int d = ds_ * 16 + l15;
#pragma unroll
            for (int r = 0; r < 4; ++r) {
                int k = kt * 64 + w * 16 + lg * 4 + r;
                att[((size_t)b * SS + k) * (NH * D) + h * 64 + d] = acc[ds_][r];
            }
        }
    }
}

// ---------- Kernel 4: out = att(4096x512) @ W_o(512x64) ----------------------
__global__ __launch_bounds__(64) void outproj_kernel(
    const float* __restrict__ att, const float* __restrict__ Wo,
    float* __restrict__ out) {
    int idx = blockIdx.x;
    int t = threadIdx.x;
    __shared__ float row[NH * D];
    const float* ap = att + (size_t)idx * (NH * D);
    for (int z = t; z < NH * D; z += 64) row[z] = ap[z];
    __syncthreads();
    float acc = 0.f;
#pragma unroll 8
    for (int z = 0; z < NH * D; ++z) acc += row[z] * Wo[(size_t)z * D + t];
    out[(size_t)idx * D + t] = acc;
}

extern "C" void kernel_launch(void* const* d_in, const int* in_sizes, int n_in,
                              void* d_out, int out_size, void* d_ws, size_t ws_size,
                              hipStream_t stream) {
    const float* q  = (const float*)d_in[0];
    const float* k  = (const float*)d_in[1];
    const float* v  = (const float*)d_in[2];
    const float* Wq = (const float*)d_in[3];
    const float* Wk = (const float*)d_in[4];
    const float* Wv = (const float*)d_in[5];
    const float* Wo = (const float*)d_in[6];
    float* out = (float*)d_out;

    const size_t PROJ = (size_t)NBH * SS * D;  // 2,097,152 elements

    short* qh  = (short*)d_ws;
    short* kh  = qh + PROJ;
    short* vhT = kh + PROJ;
    short* WqT = vhT + PROJ;
    short* WkT = WqT + 32768;
    short* WvT = WkT + 32768;
    float* marr  = (float*)(WvT + 32768);
    float* ilarr = marr + (size_t)NBH * SS;
    float* att   = ilarr + (size_t)NBH * SS;   // NBH*SS*D fp32

    wtrans_kernel<<<24, 256, 0, stream>>>(Wq, Wk, Wv, WqT, WkT, WvT);

    proj_mfma_kernel<<<NBH * 32, 256, 0, stream>>>(q, WqT, qh, nullptr, 1);
    proj_mfma_kernel<<<NBH * 32, 256, 0, stream>>>(k, WkT, kh, nullptr, 1);
    proj_mfma_kernel<<<NBH * 32, 256, 0, stream>>>(v, WvT, nullptr, vhT, 2);

    colstats_kernel<<<NBH * 16, 256, 0, stream>>>(qh, kh, marr, ilarr);

    pv_kernel<<<NBH * 16, 256, 0, stream>>>(qh, kh, vhT, marr, ilarr, att);

    outproj_kernel<<<BB * SS, 64, 0, stream>>>(att, Wo, out);
}

// Round 7
// 146.163 us; speedup vs baseline: 18.0527x; 1.0622x over previous
//
#include <hip/hip_runtime.h>
#include <math.h>

#define NH 8
#define D 64
#define BB 2
#define SS 2048
#define NBH (BB*NH)
#define LOG2E 1.4426950408889634f

typedef short bf16x8 __attribute__((ext_vector_type(8)));
typedef float f32x4 __attribute__((ext_vector_type(4)));

#define MFMA16(a,b,c) __builtin_amdgcn_mfma_f32_16x16x32_bf16((a),(b),(c),0,0,0)

// round-to-nearest-even f32 -> bf16
__device__ inline short f2bf(float f) {
    unsigned u = __float_as_uint(f);
    unsigned r = (u + 0x7fffu + ((u >> 16) & 1u)) >> 16;
    return (short)r;
}

// ---------- Kernel 0: W transposes -> bf16 ------------------------------------
// blocks 0..23: Wq/Wk/Wv [h][z][d] -> WT[h][d][z]
// blocks 24..31: Wo[z][d] (512x64) -> WoT[d][z'] (64x1024), z' = z duplicated twice
__global__ __launch_bounds__(256) void wtrans_kernel(
    const float* __restrict__ Wq, const float* __restrict__ Wk,
    const float* __restrict__ Wv, const float* __restrict__ Wo,
    short* __restrict__ WqT, short* __restrict__ WkT, short* __restrict__ WvT,
    short* __restrict__ WoT) {
    int blk = blockIdx.x;
    int t = threadIdx.x;
    if (blk < 24) {
        int tensor = blk >> 3, h = blk & 7;
        const float* W = tensor == 0 ? Wq : (tensor == 1 ? Wk : Wv);
        short* WT = tensor == 0 ? WqT : (tensor == 1 ? WkT : WvT);
        __shared__ float wl[64][65];
        {
            int z = t >> 2, c0 = (t & 3) * 16;
            const float* src = W + (size_t)h * 4096 + (size_t)z * 64 + c0;
#pragma unroll
            for (int i = 0; i < 16; ++i) wl[z][c0 + i] = src[i];
        }
        __syncthreads();
        {
            int d = t >> 2, z0 = (t & 3) * 16;
            short* dst = WT + ((size_t)h * 64 + d) * 64 + z0;
#pragma unroll
            for (int i = 0; i < 16; ++i) dst[i] = f2bf(wl[z0 + i][d]);
        }
    } else {
        int idx = (blk - 24) * 256 + t;   // 0..2047
        int d = idx >> 5;                 // 0..63
        int zc = (idx & 31) * 32;         // 0..992
#pragma unroll
        for (int j = 0; j < 32; ++j) {
            int z = zc + j;
            WoT[(size_t)d * 1024 + z] = f2bf(Wo[(size_t)(z & 511) * 64 + d]);
        }
    }
}

// ---------- Kernel 1: fused QKV projection via MFMA ---------------------------
// grid = 3*NBH*32; tensor 0: rope + 1/64 scale -> qh; 1: rope -> kh; 2: transpose -> vhT
__global__ __launch_bounds__(256) void proj_mfma_kernel(
    const float* __restrict__ xq, const float* __restrict__ xk,
    const float* __restrict__ xv,
    const short* __restrict__ WqT, const short* __restrict__ WkT,
    const short* __restrict__ WvT,
    short* __restrict__ qh, short* __restrict__ kh, short* __restrict__ vhT) {
    int blk = blockIdx.x;
    int tensor = blk / (NBH * 32);
    int rem = blk - tensor * (NBH * 32);
    int st = rem & 31, bh = rem >> 5;
    int h = bh & 7, b = bh >> 3;
    const float* x = tensor == 0 ? xq : (tensor == 1 ? xk : xv);
    const short* WT = tensor == 0 ? WqT : (tensor == 1 ? WkT : WvT);

    int t = threadIdx.x, w = t >> 6, lane = t & 63;
    int l15 = lane & 15, lg = lane >> 4;

    __shared__ short vt[64 * 64];

    int sA = st * 64 + w * 16 + l15;
    const float* xr = x + ((size_t)b * SS + sA) * D + lg * 8;
    bf16x8 a0, a1;
#pragma unroll
    for (int j = 0; j < 8; ++j) a0[j] = f2bf(xr[j]);
#pragma unroll
    for (int j = 0; j < 8; ++j) a1[j] = f2bf(xr[32 + j]);

    bf16x8 bfr[4][2];
#pragma unroll
    for (int ds_ = 0; ds_ < 4; ++ds_) {
        int d = ds_ * 16 + l15;
        const short* wp = WT + ((size_t)h * 64 + d) * 64 + lg * 8;
        bfr[ds_][0] = *(const bf16x8*)(wp);
        bfr[ds_][1] = *(const bf16x8*)(wp + 32);
    }

    f32x4 c[4];
#pragma unroll
    for (int ds_ = 0; ds_ < 4; ++ds_) {
        f32x4 z = {0.f, 0.f, 0.f, 0.f};
        z = MFMA16(a0, bfr[ds_][0], z);
        z = MFMA16(a1, bfr[ds_][1], z);
        c[ds_] = z;
    }

    int sbase = st * 64 + w * 16 + lg * 4;
    if (tensor < 2) {
        short* dst = tensor == 0 ? qh : kh;
        float scale = tensor == 0 ? (1.0f / 64.0f) : 1.0f;
#pragma unroll
        for (int ds_ = 0; ds_ < 4; ++ds_) {
            int d = ds_ * 16 + l15;
            float invf = exp2f(-(float)(d & ~1) * (13.287712379549449f / 64.0f));
#pragma unroll
            for (int r = 0; r < 4; ++r) {
                float v = c[ds_][r];
                float pr = __shfl_xor(v, 1);
                float ang = (float)(sbase + r) * invf;
                float cs = cosf(ang), sn = sinf(ang);
                float o = (d & 1) ? (pr * sn + v * cs) : (v * cs - pr * sn);
                dst[((size_t)bh * SS + sbase + r) * D + d] = f2bf(o * scale);
            }
        }
    } else {
#pragma unroll
        for (int ds_ = 0; ds_ < 4; ++ds_) {
            int d = ds_ * 16 + l15;
#pragma unroll
            for (int r = 0; r < 4; ++r) {
                int sc = w * 16 + lg * 4 + r;
                vt[d * 64 + (sc ^ ((d & 7) << 3))] = f2bf(c[ds_][r]);
            }
        }
        __syncthreads();
#pragma unroll
        for (int pp = 0; pp < 2; ++pp) {
            int idx = pp * 256 + t;
            int d = idx >> 3, a = idx & 7;
            bf16x8 val = *(const bf16x8*)&vt[d * 64 + ((a ^ (d & 7)) << 3)];
            *(bf16x8*)&vhT[((size_t)bh * D + d) * SS + st * 64 + a * 8] = val;
        }
    }
}

// ---------- Kernel 2: per-q softmax denominators (no max needed: |s| <~ 1) ----
// grid = NBH*32: blk -> (bh, pair p, k-parity ph). 512 thr: waves 0-3 -> qt=p,
// waves 4-7 -> qt=31-p. Writes partial sum for its parity class.
__global__ __launch_bounds__(512, 4) void colstats_kernel(
    const short* __restrict__ qh, const short* __restrict__ kh,
    float* __restrict__ lpart) {
    int blk = blockIdx.x;
    int ph = blk & 1, p = (blk >> 1) & 15, bh = blk >> 5;
    int t = threadIdx.x, lane = t & 63;
    int w = (t >> 6) & 3, half = t >> 8;
    int l15 = lane & 15, lg = lane >> 4;
    int qt = half ? (31 - p) : p;
    int qcol = qt * 64 + w * 16 + l15;

    const short* qp = qh + ((size_t)bh * SS + qcol) * D + lg * 8;
    bf16x8 qb0 = *(const bf16x8*)qp;
    bf16x8 qb1 = *(const bf16x8*)(qp + 32);

    const short* kbase = kh + (size_t)bh * SS * D;
    float lsum = 0.f;

    for (int kt = ph; kt <= qt; kt += 2) {
        bool diag = (kt == qt);
#pragma unroll
        for (int ks = 0; ks < 4; ++ks) {
            const short* kp = kbase + (size_t)(kt * 64 + ks * 16 + l15) * D + lg * 8;
            bf16x8 ka0 = *(const bf16x8*)kp;
            bf16x8 ka1 = *(const bf16x8*)(kp + 32);
            f32x4 sacc = {0.f, 0.f, 0.f, 0.f};
            sacc = MFMA16(ka0, qb0, sacc);
            sacc = MFMA16(ka1, qb1, sacc);
            int kb = kt * 64 + ks * 16 + lg * 4;
            // softmax denominator includes k<=q (diag removed only AFTER softmax)
            float e0 = (!diag || kb + 0 <= qcol) ? exp2f(sacc[0] * LOG2E) : 0.f;
            float e1 = (!diag || kb + 1 <= qcol) ? exp2f(sacc[1] * LOG2E) : 0.f;
            float e2 = (!diag || kb + 2 <= qcol) ? exp2f(sacc[2] * LOG2E) : 0.f;
            float e3 = (!diag || kb + 3 <= qcol) ? exp2f(sacc[3] * LOG2E) : 0.f;
            lsum += (e0 + e1) + (e2 + e3);
        }
    }
    // combine across the 4 lane-groups (same q column)
    lsum += __shfl_xor(lsum, 16);
    lsum += __shfl_xor(lsum, 32);
    if (lane < 16) {
        lpart[((size_t)ph * NBH + bh) * SS + qcol] = lsum;
    }
}

// ---------- Kernel 2b: merge the two parity partials --------------------------
__global__ __launch_bounds__(256) void merge_stats_kernel(
    const float* __restrict__ lpart, float* __restrict__ ilarr) {
    size_t idx = (size_t)blockIdx.x * 256 + threadIdx.x;
    float l0 = lpart[idx], l1 = lpart[(size_t)NBH * SS + idx];
    ilarr[idx] = 1.0f / (l0 + l1);
}

// ---------- Kernel 3: PV, barrier-free, parity-split q ------------------------
// grid = NBH*32: blk -> (bh, pair p, q-parity ph). 512 thr: waves 0-3 -> kt=p,
// waves 4-7 -> kt=31-p. attc[b][k][ph*512 + h*64 + d] (bf16), summed via
// duplicated Wo in outproj.
__global__ __launch_bounds__(512, 4) void pv_kernel(
    const short* __restrict__ qh, const short* __restrict__ kh,
    const short* __restrict__ vhT,
    const float* __restrict__ ilarr,
    short* __restrict__ attc) {
    int blk = blockIdx.x;
    int ph = blk & 1, p = (blk >> 1) & 15, bh = blk >> 5;
    int h = bh & 7, b = bh >> 3;
    int t = threadIdx.x, wv = t >> 6, lane = t & 63;
    int w = wv & 3, half = wv >> 2;
    int l15 = lane & 15, lg = lane >> 4;
    int kt = half ? (31 - p) : p;

    __shared__ short pl[8][16 * 64];
    short* plw = pl[wv];

    const short* kp = kh + ((size_t)bh * SS + kt * 64 + w * 16 + l15) * D + lg * 8;
    bf16x8 ka0 = *(const bf16x8*)kp;
    bf16x8 ka1 = *(const bf16x8*)(kp + 32);

    f32x4 acc[4];
#pragma unroll
    for (int i = 0; i < 4; ++i) acc[i] = (f32x4){0.f, 0.f, 0.f, 0.f};
    int myk = kt * 64 + w * 16 + lg * 4;

    const float* irow = ilarr + (size_t)bh * SS;
    const short* qbase = qh + (size_t)bh * SS * D;
    const short* vbase = vhT + (size_t)bh * D * SS;

    int qt0 = kt + ((kt ^ ph) & 1);
    for (int qt = qt0; qt < 32; qt += 2) {
        bool diag = (qt == kt);
#pragma unroll
        for (int qs = 0; qs < 4; ++qs) {
            int qrow = qs * 16 + l15;
            int qq = qt * 64 + qrow;
            const short* qp2 = qbase + (size_t)qq * D + lg * 8;
            bf16x8 qb0 = *(const bf16x8*)qp2;
            bf16x8 qb1 = *(const bf16x8*)(qp2 + 32);
            f32x4 s = {0.f, 0.f, 0.f, 0.f};
            s = MFMA16(ka0, qb0, s);
            s = MFMA16(ka1, qb1, s);
            float iq = irow[qq];
#pragma unroll
            for (int r = 0; r < 4; ++r) {
                float pvv = exp2f(s[r] * LOG2E) * iq;
                if (diag && qq <= myk + r) pvv = 0.f;
                int prow = lg * 4 + r;
                plw[prow * 64 + (qrow ^ ((prow & 7) << 3))] = f2bf(pvv);
            }
        }
#pragma unroll
        for (int qhh = 0; qhh < 2; ++qhh) {
            int chunk = (qhh << 2) | lg;
            bf16x8 pa = *(const bf16x8*)&plw[l15 * 64 + ((chunk ^ (l15 & 7)) << 3)];
#pragma unroll
            for (int ds_ = 0; ds_ < 4; ++ds_) {
                const short* vp2 = vbase + (size_t)(ds_ * 16 + l15) * SS + qt * 64 + chunk * 8;
                bf16x8 vb = *(const bf16x8*)vp2;
                acc[ds_] = MFMA16(pa, vb, acc[ds_]);
            }
        }
    }
#pragma unroll
    for (int ds_ = 0; ds_ < 4; ++ds_) {
        int d = ds_ * 16 + l15;
#pragma unroll
        for (int r = 0; r < 4; ++r) {
            int k = kt * 64 + w * 16 + lg * 4 + r;
            attc[((size_t)b * SS + k) * 1024 + ph * 512 + h * 64 + d] = f2bf(acc[ds_][r]);
        }
    }
}

// ---------- Kernel 4: out = attc(4096x1024) @ [Wo;Wo](1024x64) via MFMA --------
// grid = BB*SS/64 = 64 blocks, 256 thr (4 waves x 16 rows)
__global__ __launch_bounds__(256) void outproj_kernel(
    const short* __restrict__ attc, const short* __restrict__ WoT,
    float* __restrict__ out) {
    int blk = blockIdx.x;
    int t = threadIdx.x, w = t >> 6, lane = t & 63;
    int l15 = lane & 15, lg = lane >> 4;
    int srow = blk * 64 + w * 16 + l15;
    const short* arow = attc + (size_t)srow * 1024 + lg * 8;

    f32x4 acc[4];
#pragma unroll
    for (int i = 0; i < 4; ++i) acc[i] = (f32x4){0.f, 0.f, 0.f, 0.f};

#pragma unroll 8
    for (int kc = 0; kc < 32; ++kc) {
        bf16x8 af = *(const bf16x8*)(arow + kc * 32);
#pragma unroll
        for (int ds_ = 0; ds_ < 4; ++ds_) {
            bf16x8 bf_ = *(const bf16x8*)&WoT[(size_t)(ds_ * 16 + l15) * 1024 + kc * 32 + lg * 8];
            acc[ds_] = MFMA16(af, bf_, acc[ds_]);
        }
    }
#pragma unroll
    for (int ds_ = 0; ds_ < 4; ++ds_) {
        int d = ds_ * 16 + l15;
#pragma unroll
        for (int r = 0; r < 4; ++r) {
            int s = blk * 64 + w * 16 + lg * 4 + r;
            out[(size_t)s * 64 + d] = acc[ds_][r];
        }
    }
}

extern "C" void kernel_launch(void* const* d_in, const int* in_sizes, int n_in,
                              void* d_out, int out_size, void* d_ws, size_t ws_size,
                              hipStream_t stream) {
    const float* q  = (const float*)d_in[0];
    const float* k  = (const float*)d_in[1];
    const float* v  = (const float*)d_in[2];
    const float* Wq = (const float*)d_in[3];
    const float* Wk = (const float*)d_in[4];
    const float* Wv = (const float*)d_in[5];
    const float* Wo = (const float*)d_in[6];
    float* out = (float*)d_out;

    const size_t PROJ = (size_t)NBH * SS * D;

    short* qh  = (short*)d_ws;
    short* kh  = qh + PROJ;
    short* vhT = kh + PROJ;
    short* WqT = vhT + PROJ;
    short* WkT = WqT + 32768;
    short* WvT = WkT + 32768;
    short* WoT = WvT + 32768;                    // 64*1024
    float* lpart = (float*)(WoT + 65536);        // 2*NBH*SS
    float* ilarr = lpart + 2 * (size_t)NBH * SS; // NBH*SS
    short* attc  = (short*)(ilarr + (size_t)NBH * SS);  // BB*SS*1024 bf16

    wtrans_kernel<<<32, 256, 0, stream>>>(Wq, Wk, Wv, Wo, WqT, WkT, WvT, WoT);

    proj_mfma_kernel<<<3 * NBH * 32, 256, 0, stream>>>(q, k, v, WqT, WkT, WvT,
                                                       qh, kh, vhT);

    colstats_kernel<<<NBH * 32, 512, 0, stream>>>(qh, kh, lpart);

    merge_stats_kernel<<<(NBH * SS) / 256, 256, 0, stream>>>(lpart, ilarr);

    pv_kernel<<<NBH * 32, 512, 0, stream>>>(qh, kh, vhT, ilarr, attc);

    outproj_kernel<<<(BB * SS) / 64, 256, 0, stream>>>(attc, WoT, out);
}

// Round 8
// 111.954 us; speedup vs baseline: 23.5689x; 1.3056x over previous
//
#include <hip/hip_runtime.h>
#include <math.h>

#define NH 8
#define D 64
#define BB 2
#define SS 2048
#define NBH (BB*NH)
#define LOG2E 1.4426950408889634f
#define NPAR 4  // parity split width (q-parity in pv, k-parity in colstats)

typedef short bf16x8 __attribute__((ext_vector_type(8)));
typedef float f32x4 __attribute__((ext_vector_type(4)));

#define MFMA16(a,b,c) __builtin_amdgcn_mfma_f32_16x16x32_bf16((a),(b),(c),0,0,0)

// round-to-nearest-even f32 -> bf16
__device__ inline short f2bf(float f) {
    unsigned u = __float_as_uint(f);
    unsigned r = (u + 0x7fffu + ((u >> 16) & 1u)) >> 16;
    return (short)r;
}

// ---------- Kernel 0: W transposes -> bf16 ------------------------------------
// blocks 0..23: Wq/Wk/Wv [h][z][d] -> WT[h][d][z]
// blocks 24..39: Wo[z][d] (512x64) -> WoT[d][z'] (64x2048), z' = z duplicated 4x
__global__ __launch_bounds__(256) void wtrans_kernel(
    const float* __restrict__ Wq, const float* __restrict__ Wk,
    const float* __restrict__ Wv, const float* __restrict__ Wo,
    short* __restrict__ WqT, short* __restrict__ WkT, short* __restrict__ WvT,
    short* __restrict__ WoT) {
    int blk = blockIdx.x;
    int t = threadIdx.x;
    if (blk < 24) {
        int tensor = blk >> 3, h = blk & 7;
        const float* W = tensor == 0 ? Wq : (tensor == 1 ? Wk : Wv);
        short* WT = tensor == 0 ? WqT : (tensor == 1 ? WkT : WvT);
        __shared__ float wl[64][65];
        {
            int z = t >> 2, c0 = (t & 3) * 16;
            const float* src = W + (size_t)h * 4096 + (size_t)z * 64 + c0;
#pragma unroll
            for (int i = 0; i < 16; ++i) wl[z][c0 + i] = src[i];
        }
        __syncthreads();
        {
            int d = t >> 2, z0 = (t & 3) * 16;
            short* dst = WT + ((size_t)h * 64 + d) * 64 + z0;
#pragma unroll
            for (int i = 0; i < 16; ++i) dst[i] = f2bf(wl[z0 + i][d]);
        }
    } else {
        int idx = (blk - 24) * 256 + t;   // 0..4095
        int d = idx >> 6;                 // 0..63
        int zc = (idx & 63) * 32;         // 0..2016
#pragma unroll
        for (int j = 0; j < 32; ++j) {
            int z = zc + j;
            WoT[(size_t)d * 2048 + z] = f2bf(Wo[(size_t)(z & 511) * 64 + d]);
        }
    }
}

// ---------- Kernel 1: fused QKV projection via MFMA ---------------------------
// grid = 3*NBH*32; tensor 0: rope + 1/64 scale -> qh; 1: rope -> kh; 2: transpose -> vhT
__global__ __launch_bounds__(256) void proj_mfma_kernel(
    const float* __restrict__ xq, const float* __restrict__ xk,
    const float* __restrict__ xv,
    const short* __restrict__ WqT, const short* __restrict__ WkT,
    const short* __restrict__ WvT,
    short* __restrict__ qh, short* __restrict__ kh, short* __restrict__ vhT) {
    int blk = blockIdx.x;
    int tensor = blk / (NBH * 32);
    int rem = blk - tensor * (NBH * 32);
    int st = rem & 31, bh = rem >> 5;
    int h = bh & 7, b = bh >> 3;
    const float* x = tensor == 0 ? xq : (tensor == 1 ? xk : xv);
    const short* WT = tensor == 0 ? WqT : (tensor == 1 ? WkT : WvT);

    int t = threadIdx.x, w = t >> 6, lane = t & 63;
    int l15 = lane & 15, lg = lane >> 4;

    __shared__ short vt[64 * 64];

    int sA = st * 64 + w * 16 + l15;
    const float* xr = x + ((size_t)b * SS + sA) * D + lg * 8;
    bf16x8 a0, a1;
#pragma unroll
    for (int j = 0; j < 8; ++j) a0[j] = f2bf(xr[j]);
#pragma unroll
    for (int j = 0; j < 8; ++j) a1[j] = f2bf(xr[32 + j]);

    bf16x8 bfr[4][2];
#pragma unroll
    for (int ds_ = 0; ds_ < 4; ++ds_) {
        int d = ds_ * 16 + l15;
        const short* wp = WT + ((size_t)h * 64 + d) * 64 + lg * 8;
        bfr[ds_][0] = *(const bf16x8*)(wp);
        bfr[ds_][1] = *(const bf16x8*)(wp + 32);
    }

    f32x4 c[4];
#pragma unroll
    for (int ds_ = 0; ds_ < 4; ++ds_) {
        f32x4 z = {0.f, 0.f, 0.f, 0.f};
        z = MFMA16(a0, bfr[ds_][0], z);
        z = MFMA16(a1, bfr[ds_][1], z);
        c[ds_] = z;
    }

    int sbase = st * 64 + w * 16 + lg * 4;
    if (tensor < 2) {
        short* dst = tensor == 0 ? qh : kh;
        float scale = tensor == 0 ? (1.0f / 64.0f) : 1.0f;
#pragma unroll
        for (int ds_ = 0; ds_ < 4; ++ds_) {
            int d = ds_ * 16 + l15;
            float invf = exp2f(-(float)(d & ~1) * (13.287712379549449f / 64.0f));
#pragma unroll
            for (int r = 0; r < 4; ++r) {
                float v = c[ds_][r];
                float pr = __shfl_xor(v, 1);
                float ang = (float)(sbase + r) * invf;
                float cs = cosf(ang), sn = sinf(ang);
                float o = (d & 1) ? (pr * sn + v * cs) : (v * cs - pr * sn);
                dst[((size_t)bh * SS + sbase + r) * D + d] = f2bf(o * scale);
            }
        }
    } else {
#pragma unroll
        for (int ds_ = 0; ds_ < 4; ++ds_) {
            int d = ds_ * 16 + l15;
#pragma unroll
            for (int r = 0; r < 4; ++r) {
                int sc = w * 16 + lg * 4 + r;
                vt[d * 64 + (sc ^ ((d & 7) << 3))] = f2bf(c[ds_][r]);
            }
        }
        __syncthreads();
#pragma unroll
        for (int pp = 0; pp < 2; ++pp) {
            int idx = pp * 256 + t;
            int d = idx >> 3, a = idx & 7;
            bf16x8 val = *(const bf16x8*)&vt[d * 64 + ((a ^ (d & 7)) << 3)];
            *(bf16x8*)&vhT[((size_t)bh * D + d) * SS + st * 64 + a * 8] = val;
        }
    }
}

// ---------- Kernel 2: per-q softmax denominators ------------------------------
// grid = 16bh * 8p * 4ph = 512 blocks, 256 thr (4 waves).
// Wave w owns a FULL 64-q tile: qt in {p, 31-p, p+8, 23-p}; iterates kt of its
// parity class. Q B-frags register-resident; K loaded once per tile step.
__global__ __launch_bounds__(256, 4) void colstats_kernel(
    const short* __restrict__ qh, const short* __restrict__ kh,
    float* __restrict__ lpart) {
    int blk = blockIdx.x;
    int ph = blk & 3, p = (blk >> 2) & 7, bh = blk >> 5;
    int t = threadIdx.x, w = t >> 6, lane = t & 63;
    int l15 = lane & 15, lg = lane >> 4;
    int qt = (w & 1) ? ((w >> 1) ? (23 - p) : (31 - p))
                     : ((w >> 1) ? (p + 8) : p);

    // Q B-frags for the whole tile (qs = 0..3)
    bf16x8 qb[4][2];
#pragma unroll
    for (int qs = 0; qs < 4; ++qs) {
        const short* qp = qh + ((size_t)bh * SS + qt * 64 + qs * 16 + l15) * D + lg * 8;
        qb[qs][0] = *(const bf16x8*)qp;
        qb[qs][1] = *(const bf16x8*)(qp + 32);
    }

    const short* kbase = kh + (size_t)bh * SS * D;
    float lsum[4] = {0.f, 0.f, 0.f, 0.f};

    for (int kt = ph; kt <= qt; kt += NPAR) {
        bool diag = (kt == qt);
#pragma unroll
        for (int ks = 0; ks < 4; ++ks) {
            const short* kp = kbase + (size_t)(kt * 64 + ks * 16 + l15) * D + lg * 8;
            bf16x8 ka0 = *(const bf16x8*)kp;
            bf16x8 ka1 = *(const bf16x8*)(kp + 32);
            int kb = kt * 64 + ks * 16 + lg * 4;
#pragma unroll
            for (int qs = 0; qs < 4; ++qs) {
                f32x4 s = {0.f, 0.f, 0.f, 0.f};
                s = MFMA16(ka0, qb[qs][0], s);
                s = MFMA16(ka1, qb[qs][1], s);
                int qc = qt * 64 + qs * 16 + l15;
#pragma unroll
                for (int r = 0; r < 4; ++r) {
                    float e = (!diag || kb + r <= qc) ? exp2f(s[r] * LOG2E) : 0.f;
                    lsum[qs] += e;
                }
            }
        }
    }
#pragma unroll
    for (int qs = 0; qs < 4; ++qs) {
        lsum[qs] += __shfl_xor(lsum[qs], 16);
        lsum[qs] += __shfl_xor(lsum[qs], 32);
    }
    if (lane < 16) {
#pragma unroll
        for (int qs = 0; qs < 4; ++qs)
            lpart[((size_t)ph * NBH + bh) * SS + qt * 64 + qs * 16 + lane] = lsum[qs];
    }
}

// ---------- Kernel 2b: merge the four parity partials -------------------------
__global__ __launch_bounds__(256) void merge_stats_kernel(
    const float* __restrict__ lpart, float* __restrict__ ilarr) {
    size_t idx = (size_t)blockIdx.x * 256 + threadIdx.x;
    const size_t STR = (size_t)NBH * SS;
    float l = lpart[idx] + lpart[STR + idx] + lpart[2 * STR + idx] + lpart[3 * STR + idx];
    ilarr[idx] = 1.0f / l;
}

// ---------- Kernel 3: PV ------------------------------------------------------
// grid = 16bh * 16p * 4ph = 1024 blocks, 256 thr (4 waves).
// Wave w: kt = (w&1)? 31-p : p, half hf = w>>1 -> owns 32 k-rows (K frags +
// 32-reg f32 acc register-resident). Iterates qt >= kt with qt = ph (mod 4).
// attc[b][k][ph*512 + h*64 + d] bf16; summed via 4x-duplicated Wo in outproj.
__global__ __launch_bounds__(256, 4) void pv_kernel(
    const short* __restrict__ qh, const short* __restrict__ kh,
    const short* __restrict__ vhT,
    const float* __restrict__ ilarr,
    short* __restrict__ attc) {
    int blk = blockIdx.x;
    int ph = blk & 3, p = (blk >> 2) & 15, bh = blk >> 6;
    int h = bh & 7, b = bh >> 3;
    int t = threadIdx.x, w = t >> 6, lane = t & 63;
    int l15 = lane & 15, lg = lane >> 4;
    int kt = (w & 1) ? (31 - p) : p;
    int hf = w >> 1;
    int row0 = kt * 64 + hf * 32;

    __shared__ short pl[4][32 * 64];
    short* plw = pl[w];

    // K A-frags for the wave's 32 k-rows (rg = 0,1)
    bf16x8 ka[2][2];
#pragma unroll
    for (int rg = 0; rg < 2; ++rg) {
        const short* kp = kh + ((size_t)bh * SS + row0 + rg * 16 + l15) * D + lg * 8;
        ka[rg][0] = *(const bf16x8*)kp;
        ka[rg][1] = *(const bf16x8*)(kp + 32);
    }

    f32x4 acc[2][4];
#pragma unroll
    for (int rg = 0; rg < 2; ++rg)
#pragma unroll
        for (int i = 0; i < 4; ++i) acc[rg][i] = (f32x4){0.f, 0.f, 0.f, 0.f};

    int myk0 = row0 + lg * 4;  // + rg*16 + r
    const float* irow = ilarr + (size_t)bh * SS;
    const short* qbase = qh + (size_t)bh * SS * D;
    const short* vbase = vhT + (size_t)bh * D * SS;

    int qt0 = kt + ((ph - kt) & 3);
    for (int qt = qt0; qt < 32; qt += NPAR) {
        bool diag = (qt == kt);
        // Q B-frags for this tile
        bf16x8 qb[4][2];
#pragma unroll
        for (int qs = 0; qs < 4; ++qs) {
            const short* qp2 = qbase + (size_t)(qt * 64 + qs * 16 + l15) * D + lg * 8;
            qb[qs][0] = *(const bf16x8*)qp2;
            qb[qs][1] = *(const bf16x8*)(qp2 + 32);
        }
        // QK^T + exp + P-write (wave-private LDS, no barrier)
#pragma unroll
        for (int qs = 0; qs < 4; ++qs) {
            int qrow = qs * 16 + l15;
            int qq = qt * 64 + qrow;
            float iq = irow[qq];
            f32x4 s0 = {0.f, 0.f, 0.f, 0.f};
            s0 = MFMA16(ka[0][0], qb[qs][0], s0);
            s0 = MFMA16(ka[0][1], qb[qs][1], s0);
            f32x4 s1 = {0.f, 0.f, 0.f, 0.f};
            s1 = MFMA16(ka[1][0], qb[qs][0], s1);
            s1 = MFMA16(ka[1][1], qb[qs][1], s1);
#pragma unroll
            for (int r = 0; r < 4; ++r) {
                float p0 = exp2f(s0[r] * LOG2E) * iq;
                float p1 = exp2f(s1[r] * LOG2E) * iq;
                if (diag && qq <= myk0 + r) p0 = 0.f;
                if (diag && qq <= myk0 + 16 + r) p1 = 0.f;
                int pr0 = lg * 4 + r;
                int pr1 = 16 + lg * 4 + r;
                plw[pr0 * 64 + (qrow ^ ((pr0 & 7) << 3))] = f2bf(p0);
                plw[pr1 * 64 + (qrow ^ ((pr1 & 7) << 3))] = f2bf(p1);
            }
        }
        // PV: A = P' rows (prow_r = rg*16 + l15); V B-frags shared across rg
#pragma unroll
        for (int qhh = 0; qhh < 2; ++qhh) {
            int chunk = (qhh << 2) | lg;
            bf16x8 pa0 = *(const bf16x8*)&plw[l15 * 64 + ((chunk ^ (l15 & 7)) << 3)];
            bf16x8 pa1 = *(const bf16x8*)&plw[(16 + l15) * 64 + ((chunk ^ (l15 & 7)) << 3)];
#pragma unroll
            for (int ds_ = 0; ds_ < 4; ++ds_) {
                const short* vp2 = vbase + (size_t)(ds_ * 16 + l15) * SS + qt * 64 + chunk * 8;
                bf16x8 vb = *(const bf16x8*)vp2;
                acc[0][ds_] = MFMA16(pa0, vb, acc[0][ds_]);
                acc[1][ds_] = MFMA16(pa1, vb, acc[1][ds_]);
            }
        }
    }
#pragma unroll
    for (int rg = 0; rg < 2; ++rg)
#pragma unroll
        for (int ds_ = 0; ds_ < 4; ++ds_) {
            int d = ds_ * 16 + l15;
#pragma unroll
            for (int r = 0; r < 4; ++r) {
                int k = row0 + rg * 16 + lg * 4 + r;
                attc[((size_t)b * SS + k) * 2048 + ph * 512 + h * 64 + d] =
                    f2bf(acc[rg][ds_][r]);
            }
        }
}

// ---------- Kernel 4: out = attc(4096x2048) @ [Wo x4](2048x64) via MFMA -------
// grid = 256 blocks, 256 thr: block = 16 s-rows; wave w covers K-chunk
// kc in [w*16, w*16+16); f32 reduce across waves through LDS.
__global__ __launch_bounds__(256) void outproj_kernel(
    const short* __restrict__ attc, const short* __restrict__ WoT,
    float* __restrict__ out) {
    int blk = blockIdx.x;
    int t = threadIdx.x, w = t >> 6, lane = t & 63;
    int l15 = lane & 15, lg = lane >> 4;
    int srow = blk * 16 + l15;
    const short* arow = attc + (size_t)srow * 2048 + lg * 8;

    f32x4 acc[4];
#pragma unroll
    for (int i = 0; i < 4; ++i) acc[i] = (f32x4){0.f, 0.f, 0.f, 0.f};

#pragma unroll
    for (int i = 0; i < 16; ++i) {
        int kc = w * 16 + i;
        bf16x8 af = *(const bf16x8*)(arow + kc * 32);
#pragma unroll
        for (int ds_ = 0; ds_ < 4; ++ds_) {
            bf16x8 bf_ = *(const bf16x8*)&WoT[(size_t)(ds_ * 16 + l15) * 2048 + kc * 32 + lg * 8];
            acc[ds_] = MFMA16(af, bf_, acc[ds_]);
        }
    }
    __shared__ float red[4][16 * 64];
#pragma unroll
    for (int ds_ = 0; ds_ < 4; ++ds_)
#pragma unroll
        for (int r = 0; r < 4; ++r)
            red[w][(lg * 4 + r) * 64 + ds_ * 16 + l15] = acc[ds_][r];
    __syncthreads();
    {
        int idx4 = t * 4;
        int row = idx4 >> 6, col = idx4 & 63;
        float4 s0 = *(const float4*)&red[0][row * 64 + col];
        float4 s1 = *(const float4*)&red[1][row * 64 + col];
        float4 s2 = *(const float4*)&red[2][row * 64 + col];
        float4 s3 = *(const float4*)&red[3][row * 64 + col];
        float4 sum;
        sum.x = s0.x + s1.x + s2.x + s3.x;
        sum.y = s0.y + s1.y + s2.y + s3.y;
        sum.z = s0.z + s1.z + s2.z + s3.z;
        sum.w = s0.w + s1.w + s2.w + s3.w;
        *(float4*)&out[(size_t)(blk * 16 + row) * 64 + col] = sum;
    }
}

extern "C" void kernel_launch(void* const* d_in, const int* in_sizes, int n_in,
                              void* d_out, int out_size, void* d_ws, size_t ws_size,
                              hipStream_t stream) {
    const float* q  = (const float*)d_in[0];
    const float* k  = (const float*)d_in[1];
    const float* v  = (const float*)d_in[2];
    const float* Wq = (const float*)d_in[3];
    const float* Wk = (const float*)d_in[4];
    const float* Wv = (const float*)d_in[5];
    const float* Wo = (const float*)d_in[6];
    float* out = (float*)d_out;

    const size_t PROJ = (size_t)NBH * SS * D;

    short* qh  = (short*)d_ws;
    short* kh  = qh + PROJ;
    short* vhT = kh + PROJ;
    short* WqT = vhT + PROJ;
    short* WkT = WqT + 32768;
    short* WvT = WkT + 32768;
    short* WoT = WvT + 32768;                     // 64*2048
    float* lpart = (float*)(WoT + 131072);        // 4*NBH*SS
    float* ilarr = lpart + 4 * (size_t)NBH * SS;  // NBH*SS
    short* attc  = (short*)(ilarr + (size_t)NBH * SS);  // BB*SS*2048 bf16

    wtrans_kernel<<<40, 256, 0, stream>>>(Wq, Wk, Wv, Wo, WqT, WkT, WvT, WoT);

    proj_mfma_kernel<<<3 * NBH * 32, 256, 0, stream>>>(q, k, v, WqT, WkT, WvT,
                                                       qh, kh, vhT);

    colstats_kernel<<<NBH * 32, 256, 0, stream>>>(qh, kh, lpart);

    merge_stats_kernel<<<(NBH * SS) / 256, 256, 0, stream>>>(lpart, ilarr);

    pv_kernel<<<NBH * 64, 256, 0, stream>>>(qh, kh, vhT, ilarr, attc);

    outproj_kernel<<<256, 256, 0, stream>>>(attc, WoT, out);
}